// Round 6
// baseline (101.989 us; speedup 1.0000x reference)
//
#include <hip/hip_runtime.h>
#include <cstdint>
#include <cstddef>

#define MROWS 1024
#define NCOLS 4096
#define TOPK 16

typedef unsigned long long u64;
typedef unsigned int u32;

// Order-preserving float->u32 map (total order, matches score order exactly).
__device__ inline u32 fkey(u32 b) { return (b & 0x80000000u) ? ~b : (b | 0x80000000u); }

// key = (ord << 22) | ((1023-row) << 12) | (4095-col)   (54 bits used)
__device__ inline int key_col(u64 k) { return (NCOLS - 1) - (int)(k & 0xFFFull); }
__device__ inline int key_row(u64 k) { return (MROWS - 1) - (int)((k >> 12) & 0x3FFull); }

// single-wave LDS ordering fence: wait LDS only, do NOT drain vmcnt
#define WAVE_FENCE() __asm__ volatile("s_waitcnt lgkmcnt(0)" ::: "memory")

__device__ inline float wave_sum_f(float v) {
    #pragma unroll
    for (int off = 32; off >= 1; off >>= 1)
        v += __shfl_xor(v, off, 64);
    return v;
}
__device__ inline u64 wave_max_u64(u64 v) {
    #pragma unroll
    for (int off = 32; off >= 1; off >>= 1) {
        u64 o = __shfl_xor(v, off, 64);
        v = o > v ? o : v;
    }
    return v;
}
__device__ inline u64 umax64(u64 a, u64 b) { return a > b ? a : b; }

// ---- register-guaranteed sorting network on NAMED scalars (no arrays, no
// dynamic indexing -> cannot be demoted to scratch). CED: x>=y after. --------
#define CED(x, y) do { u64 _mx = (x) > (y) ? (x) : (y); \
                       u64 _mn = (x) > (y) ? (y) : (x); (x) = _mx; (y) = _mn; } while (0)
#define CEA(x, y) CED(y, x)

// bitonic merge, 16 named slots, descending (input bitonic)
#define BMERGE16D \
    CED(a0,a8); CED(a1,a9); CED(a2,a10); CED(a3,a11); CED(a4,a12); CED(a5,a13); CED(a6,a14); CED(a7,a15); \
    CED(a0,a4); CED(a1,a5); CED(a2,a6);  CED(a3,a7);  CED(a8,a12); CED(a9,a13); CED(a10,a14); CED(a11,a15); \
    CED(a0,a2); CED(a1,a3); CED(a4,a6);  CED(a5,a7);  CED(a8,a10); CED(a9,a11); CED(a12,a14); CED(a13,a15); \
    CED(a0,a1); CED(a2,a3); CED(a4,a5);  CED(a6,a7);  CED(a8,a9);  CED(a10,a11); CED(a12,a13); CED(a14,a15);

// full bitonic sort-16, descending
#define SORT16D \
    CED(a0,a1); CEA(a2,a3); CED(a4,a5); CEA(a6,a7); CED(a8,a9); CEA(a10,a11); CED(a12,a13); CEA(a14,a15); \
    CED(a0,a2); CED(a1,a3); CEA(a4,a6); CEA(a5,a7); CED(a8,a10); CED(a9,a11); CEA(a12,a14); CEA(a13,a15); \
    CED(a0,a1); CED(a2,a3); CEA(a4,a5); CEA(a6,a7); CED(a8,a9); CED(a10,a11); CEA(a12,a13); CEA(a14,a15); \
    CED(a0,a4); CED(a1,a5); CED(a2,a6); CED(a3,a7); CEA(a8,a12); CEA(a9,a13); CEA(a10,a14); CEA(a11,a15); \
    CED(a0,a2); CED(a1,a3); CED(a4,a6); CED(a5,a7); CEA(a8,a10); CEA(a9,a11); CEA(a12,a14); CEA(a13,a15); \
    CED(a0,a1); CED(a2,a3); CED(a4,a5); CED(a6,a7); CEA(a8,a9); CEA(a10,a11); CEA(a12,a13); CEA(a14,a15); \
    BMERGE16D

// top-16 of two descending-sorted 16-lists (a, b) -> bitonic in a
#define HALFCLEAN \
    a0 = umax64(a0,b15); a1 = umax64(a1,b14); a2 = umax64(a2,b13); a3 = umax64(a3,b12); \
    a4 = umax64(a4,b11); a5 = umax64(a5,b10); a6 = umax64(a6,b9);  a7 = umax64(a7,b8);  \
    a8 = umax64(a8,b7);  a9 = umax64(a9,b6);  a10 = umax64(a10,b5); a11 = umax64(a11,b4); \
    a12 = umax64(a12,b3); a13 = umax64(a13,b2); a14 = umax64(a14,b1); a15 = umax64(a15,b0);

#define LDS_STORE(idx) \
    lists[0][idx]=a0; lists[1][idx]=a1; lists[2][idx]=a2; lists[3][idx]=a3; \
    lists[4][idx]=a4; lists[5][idx]=a5; lists[6][idx]=a6; lists[7][idx]=a7; \
    lists[8][idx]=a8; lists[9][idx]=a9; lists[10][idx]=a10; lists[11][idx]=a11; \
    lists[12][idx]=a12; lists[13][idx]=a13; lists[14][idx]=a14; lists[15][idx]=a15;

#define LDS_LOADB(idx) \
    b0=lists[0][idx]; b1=lists[1][idx]; b2=lists[2][idx]; b3=lists[3][idx]; \
    b4=lists[4][idx]; b5=lists[5][idx]; b6=lists[6][idx]; b7=lists[7][idx]; \
    b8=lists[8][idx]; b9=lists[9][idx]; b10=lists[10][idx]; b11=lists[11][idx]; \
    b12=lists[12][idx]; b13=lists[13][idx]; b14=lists[14][idx]; b15=lists[15][idx];

#define MERGE_LEVEL(idx) LDS_LOADB(idx); HALFCLEAN; BMERGE16D;

// ---------------- K1: per-row top-16 score-keys + exp-sum ---------------------
// Per-thread register bitonic sort-16 (named scalars -> guaranteed VGPRs),
// then an LDS merge tree; levels <=64 wave-0-internal with lgkmcnt fences.
__global__ __launch_bounds__(256, 2) void k_prep(const float* __restrict__ s,
                                                 float* __restrict__ rowsum,
                                                 u64* __restrict__ outkeys) {
    __shared__ u64 lists[16][256];   // 32 KiB, transposed: elem i of thread t
    __shared__ float fred[4];
    int r = blockIdx.x, t = threadIdx.x;
    int wid = t >> 6, lane = t & 63;

    const float4* s4 = (const float4*)(s + (size_t)r * NCOLS);
    u64 rowpart = (u64)(MROWS - 1 - r) << 12;
    u64 a0,a1,a2,a3,a4,a5,a6,a7,a8,a9,a10,a11,a12,a13,a14,a15;
    u64 b0,b1,b2,b3,b4,b5,b6,b7,b8,b9,b10,b11,b12,b13,b14,b15;
    float acc;
    {
        float4 v0 = s4[t], v1 = s4[t + 256], v2 = s4[t + 512], v3 = s4[t + 768];
        acc  = __expf(v0.x) + __expf(v0.y) + __expf(v0.z) + __expf(v0.w);
        acc += __expf(v1.x) + __expf(v1.y) + __expf(v1.z) + __expf(v1.w);
        acc += __expf(v2.x) + __expf(v2.y) + __expf(v2.z) + __expf(v2.w);
        acc += __expf(v3.x) + __expf(v3.y) + __expf(v3.z) + __expf(v3.w);
        int c0 = 4 * t, c1 = 4 * (t + 256), c2 = 4 * (t + 512), c3 = 4 * (t + 768);
        a0  = ((u64)fkey(__float_as_uint(v0.x)) << 22) | rowpart | (u64)(NCOLS - 1 - (c0 + 0));
        a1  = ((u64)fkey(__float_as_uint(v0.y)) << 22) | rowpart | (u64)(NCOLS - 1 - (c0 + 1));
        a2  = ((u64)fkey(__float_as_uint(v0.z)) << 22) | rowpart | (u64)(NCOLS - 1 - (c0 + 2));
        a3  = ((u64)fkey(__float_as_uint(v0.w)) << 22) | rowpart | (u64)(NCOLS - 1 - (c0 + 3));
        a4  = ((u64)fkey(__float_as_uint(v1.x)) << 22) | rowpart | (u64)(NCOLS - 1 - (c1 + 0));
        a5  = ((u64)fkey(__float_as_uint(v1.y)) << 22) | rowpart | (u64)(NCOLS - 1 - (c1 + 1));
        a6  = ((u64)fkey(__float_as_uint(v1.z)) << 22) | rowpart | (u64)(NCOLS - 1 - (c1 + 2));
        a7  = ((u64)fkey(__float_as_uint(v1.w)) << 22) | rowpart | (u64)(NCOLS - 1 - (c1 + 3));
        a8  = ((u64)fkey(__float_as_uint(v2.x)) << 22) | rowpart | (u64)(NCOLS - 1 - (c2 + 0));
        a9  = ((u64)fkey(__float_as_uint(v2.y)) << 22) | rowpart | (u64)(NCOLS - 1 - (c2 + 1));
        a10 = ((u64)fkey(__float_as_uint(v2.z)) << 22) | rowpart | (u64)(NCOLS - 1 - (c2 + 2));
        a11 = ((u64)fkey(__float_as_uint(v2.w)) << 22) | rowpart | (u64)(NCOLS - 1 - (c2 + 3));
        a12 = ((u64)fkey(__float_as_uint(v3.x)) << 22) | rowpart | (u64)(NCOLS - 1 - (c3 + 0));
        a13 = ((u64)fkey(__float_as_uint(v3.y)) << 22) | rowpart | (u64)(NCOLS - 1 - (c3 + 1));
        a14 = ((u64)fkey(__float_as_uint(v3.z)) << 22) | rowpart | (u64)(NCOLS - 1 - (c3 + 2));
        a15 = ((u64)fkey(__float_as_uint(v3.w)) << 22) | rowpart | (u64)(NCOLS - 1 - (c3 + 3));
    }

    SORT16D;                         // my 16 keys, descending, in registers

    acc = wave_sum_f(acc);
    if (lane == 0) fred[wid] = acc;

    LDS_STORE(t);
    __syncthreads();
    if (t == 0) rowsum[r] = fred[0] + fred[1] + fred[2] + fred[3];

    // level 128 (cross-wave)
    if (t < 128) {
        MERGE_LEVEL(t + 128);
        LDS_STORE(t);
    }
    __syncthreads();

    // levels 64..1: wave-0-internal; lgkmcnt fence instead of __syncthreads
    if (t < 64) {
        MERGE_LEVEL(t + 64);
        LDS_STORE(t);
        WAVE_FENCE();
        if (t < 32) { MERGE_LEVEL(t + 32); LDS_STORE(t); }
        WAVE_FENCE();
        if (t < 16) { MERGE_LEVEL(t + 16); LDS_STORE(t); }
        WAVE_FENCE();
        if (t < 8)  { MERGE_LEVEL(t + 8);  LDS_STORE(t); }
        WAVE_FENCE();
        if (t < 4)  { MERGE_LEVEL(t + 4);  LDS_STORE(t); }
        WAVE_FENCE();
        if (t < 2)  { MERGE_LEVEL(t + 2);  LDS_STORE(t); }
        WAVE_FENCE();
        if (t == 0) {
            MERGE_LEVEL(1);
            u64* ok = outkeys + (size_t)r * TOPK;
            ok[0]=a0; ok[1]=a1; ok[2]=a2; ok[3]=a3; ok[4]=a4; ok[5]=a5; ok[6]=a6; ok[7]=a7;
            ok[8]=a8; ok[9]=a9; ok[10]=a10; ok[11]=a11; ok[12]=a12; ok[13]=a13; ok[14]=a14; ok[15]=a15;
        }
    }
}

// Batched prune: issue all 16 coldone word-loads independently (one lgkmcnt
// drain, not 16 serial ~120cy probes), then prune registers-only.
__device__ inline u64 prune_and_best(u64* kk, const unsigned* coldone) {
    u32 cw[TOPK];
    #pragma unroll
    for (int k = 0; k < TOPK; ++k) {
        int c = key_col(kk[k]);          // dead key -> col 4095, harmless read
        cw[k] = coldone[c >> 5];
    }
    u64 best = 0ull;
    #pragma unroll
    for (int k = 0; k < TOPK; ++k) {
        int c = key_col(kk[k]);
        if ((cw[k] >> (c & 31)) & 1u) kk[k] = 0ull;
        best = umax64(best, kk[k]);
    }
    return best;
}

// ---------------- K2: block 0 = match (parallel rounds); rest = policy --------
// Match: dominant-edge rounds, 512 threads x 2 rows, keys in registers.
// Identical to serial greedy since keys distinct; colbest tagged by round.
__global__ __launch_bounds__(512, 1) void k_policy_match(const float* __restrict__ s,
                                                         const int* __restrict__ cont,
                                                         const int* __restrict__ prev,
                                                         const float* __restrict__ rowsum,
                                                         const u64* __restrict__ keys_g,
                                                         float* __restrict__ policy,
                                                         float* __restrict__ actions) {
    __shared__ u64 colbest[NCOLS];             // 32 KiB (match only)
    __shared__ unsigned coldone[NCOLS / 32];   // 512 B
    __shared__ unsigned rowdone[MROWS / 32];   // 128 B
    __shared__ float act[MROWS];               // 4 KiB
    __shared__ float fredf[8];

    int t = threadIdx.x;
    int wid = t >> 6, lane = t & 63;

    if (blockIdx.x != 0) {
        // ---------------- policy row write (512 thr, 2 float4/thr) ------------
        int r = blockIdx.x - 1;
        const float4* srow4 = (const float4*)(s + (size_t)r * NCOLS);
        float4 v0 = srow4[t], v1 = srow4[t + 512];   // fly during the reduce
        float sv = rowsum[t] + rowsum[t + 512];
        sv = wave_sum_f(sv);
        if (lane == 0) fredf[wid] = sv;
        __syncthreads();
        float g = 0.0f;
        #pragma unroll
        for (int i = 0; i < 8; ++i) g += fredf[i];   // same order every block
        float inv = 1.0f / g;
        float4* prow4 = (float4*)(policy + (size_t)r * NCOLS);
        float4 p;
        p.x = __expf(v0.x) * inv; p.y = __expf(v0.y) * inv;
        p.z = __expf(v0.z) * inv; p.w = __expf(v0.w) * inv;
        prow4[t] = p;
        p.x = __expf(v1.x) * inv; p.y = __expf(v1.y) * inv;
        p.z = __expf(v1.z) * inv; p.w = __expf(v1.w) * inv;
        prow4[t + 512] = p;
        return;
    }

    // ---------------- match: thread t owns rows t and t+512 -------------------
    #pragma unroll
    for (int i = 0; i < 8; ++i) colbest[t + i * 512] = 0ull;
    if (t < 128) coldone[t] = 0u;
    if (t < 32) rowdone[t] = 0u;
    __syncthreads();   // zeroing ordered before the atomics below

    int r0 = t, r1 = t + 512;
    int c0f = cont[r0], c1f = cont[r1];
    int p0 = prev[r0], p1 = prev[r1];
    act[r0] = c0f ? (float)p0 : -1.0f;
    act[r1] = c1f ? (float)p1 : -1.0f;
    if (c0f) {
        atomicOr(&rowdone[r0 >> 5], 1u << (r0 & 31));
        atomicOr(&coldone[p0 >> 5], 1u << (p0 & 31));
    }
    if (c1f) {
        atomicOr(&rowdone[r1 >> 5], 1u << (r1 & 31));
        atomicOr(&coldone[p1 >> 5], 1u << (p1 & 31));
    }
    bool act0 = (c0f == 0), act1 = (c1f == 0);

    u64 k0[TOPK], k1[TOPK];
    {
        const u64* g0 = keys_g + (size_t)r0 * TOPK;
        const u64* g1 = keys_g + (size_t)r1 * TOPK;
        #pragma unroll
        for (int k = 0; k < TOPK; ++k) { k0[k] = g0[k]; k1[k] = g1[k]; }
    }
    __syncthreads();

    for (int round = 1; round < 400; ++round) {
        u64 tag = (u64)round << 54;
        bool sub0 = false, sub1 = false;
        u64 best0 = 0ull, best1 = 0ull;
        if (act0) {
            best0 = prune_and_best(k0, coldone);
            if (best0 == 0ull) act0 = false;      // exhausted -> fallback later
            else {
                sub0 = true;
                #pragma unroll
                for (int k = 0; k < TOPK; ++k)
                    if (k0[k] != 0ull)
                        atomicMax((u64*)&colbest[key_col(k0[k])], tag | k0[k]);
            }
        }
        if (act1) {
            best1 = prune_and_best(k1, coldone);
            if (best1 == 0ull) act1 = false;
            else {
                sub1 = true;
                #pragma unroll
                for (int k = 0; k < TOPK; ++k)
                    if (k1[k] != 0ull)
                        atomicMax((u64*)&colbest[key_col(k1[k])], tag | k1[k]);
            }
        }
        __syncthreads();                          // submissions visible
        // batched commit probes (independent LDS reads)
        u64 cb0 = sub0 ? colbest[key_col(best0)] : 0ull;
        u64 cb1 = sub1 ? colbest[key_col(best1)] : 0ull;
        if (sub0 && cb0 == (tag | best0)) {
            int c = key_col(best0);
            unsigned old = atomicOr(&coldone[c >> 5], 1u << (c & 31));
            if (!(old & (1u << (c & 31)))) {
                act[r0] = (float)c;
                atomicOr(&rowdone[r0 >> 5], 1u << (r0 & 31));
                act0 = false;
            }
        }
        if (sub1 && cb1 == (tag | best1)) {
            int c = key_col(best1);
            unsigned old = atomicOr(&coldone[c >> 5], 1u << (c & 31));
            if (!(old & (1u << (c & 31)))) {
                act[r1] = (float)c;
                atomicOr(&rowdone[r1 >> 5], 1u << (r1 & 31));
                act1 = false;
            }
        }
        int left = __syncthreads_count((act0 || act1) ? 1 : 0);  // commit barrier
        if (left == 0) break;
    }
    __syncthreads();

    // ---- exact-greedy fallback for exhausted rows (P ~ 1e-7 at depth 16) -----
    if (t < 64) {
        unsigned miss = (t < 32) ? ~rowdone[t] : 0u;
        if (__ballot(miss != 0u) != 0ull) {
            for (int guard = 0; guard < 1200; ++guard) {
                u64 best = 0ull;
                for (int rr = 0; rr < MROWS; ++rr) {
                    if ((rowdone[rr >> 5] >> (rr & 31)) & 1u) continue;
                    const float* srow = s + (size_t)rr * NCOLS;
                    u64 rp = (u64)(MROWS - 1 - rr) << 12;
                    for (int c = t; c < NCOLS; c += 64) {
                        if ((coldone[c >> 5] >> (c & 31)) & 1u) continue;
                        u64 kk = ((u64)fkey(__float_as_uint(srow[c])) << 22) | rp |
                                 (u64)(NCOLS - 1 - c);
                        best = umax64(best, kk);
                    }
                }
                best = wave_max_u64(best);
                if (best == 0ull) break;
                if (t == 0) {
                    int row = key_row(best), col = key_col(best);
                    rowdone[row >> 5] |= 1u << (row & 31);
                    coldone[col >> 5] |= 1u << (col & 31);
                    act[row] = (float)col;
                }
                WAVE_FENCE();
            }
        }
    }
    __syncthreads();
    actions[t] = act[t];
    actions[t + 512] = act[t + 512];
}

extern "C" void kernel_launch(void* const* d_in, const int* in_sizes, int n_in,
                              void* d_out, int out_size, void* d_ws, size_t ws_size,
                              hipStream_t stream) {
    (void)in_sizes; (void)n_in; (void)out_size; (void)ws_size;
    const float* scores = (const float*)d_in[0];
    const int* cont = (const int*)d_in[1];
    const int* prev = (const int*)d_in[2];
    float* out = (float*)d_out;
    float* actions = out;
    float* policy = out + MROWS;

    char* ws = (char*)d_ws;
    float* rowsum = (float*)(ws + 0);            // 1024 f
    u64* keys16 = (u64*)(ws + 8192);             // 1024*16 u64 = 128 KiB

    k_prep<<<MROWS, 256, 0, stream>>>(scores, rowsum, keys16);
    k_policy_match<<<MROWS + 1, 512, 0, stream>>>(scores, cont, prev, rowsum,
                                                  keys16, policy, actions);
}